// Round 8
// baseline (135.201 us; speedup 1.0000x reference)
//
#include <hip/hip_runtime.h>
#include <stdint.h>

#define N 2048
#define TILE 128
#define BK 64
#define KH 16            // K-steps per half-pipeline (2 halves x 16 = 32 total)
#define RSTR 16          // f32 row stride for the K-half exchange slots (16 slots x 4KB = 64KB = sizeof(As))
#define NN ((size_t)N * (size_t)N)

typedef unsigned short u16;
typedef __bf16 bf16x8 __attribute__((ext_vector_type(8)));
typedef unsigned short ushortx8 __attribute__((ext_vector_type(8)));
typedef float floatx4 __attribute__((ext_vector_type(4)));

static __device__ __forceinline__ u16 f2bf(float f) {
  unsigned int u = __builtin_bit_cast(unsigned int, f);
  return (u16)((u + 0x7fffu + ((u >> 16) & 1u)) >> 16);  // RNE, finite inputs
}
static __device__ __forceinline__ float bf2f(u16 h) {
  unsigned int u = ((unsigned int)h) << 16;
  return __builtin_bit_cast(float, u);
}

// async global->LDS, 16B per lane. LDS dest is wave-uniform base + lane*16
// (m104); global src is per-lane (m173) — swizzling is done on the SOURCE.
static __device__ __forceinline__ void gload16(const u16* g, u16* l) {
  __builtin_amdgcn_global_load_lds(
      (const __attribute__((address_space(1))) void*)g,
      (__attribute__((address_space(3))) void*)l, 16, 0, 0);
}

// ---------------------------------------------------------------------------
// cast + transpose: Ab[r][c] = bf16(A[r][c]); Abt[c][r] = bf16(A[r][c])
// ---------------------------------------------------------------------------
__global__ void cast_tr(const float* __restrict__ A, u16* __restrict__ Ab,
                        u16* __restrict__ Abt) {
  __shared__ float tile[32][33];
  const int tx = threadIdx.x, ty = threadIdx.y;
  const int c = blockIdx.x * 32 + tx;
#pragma unroll
  for (int i = 0; i < 4; i++) {
    const int r = blockIdx.y * 32 + ty + i * 8;
    const float v = A[(size_t)r * N + c];
    Ab[(size_t)r * N + c] = f2bf(v);
    tile[ty + i * 8][tx] = v;
  }
  __syncthreads();
  const int r2 = blockIdx.y * 32 + tx;
#pragma unroll
  for (int i = 0; i < 4; i++) {
    const int c2 = blockIdx.x * 32 + ty + i * 8;
    Abt[(size_t)c2 * N + r2] = f2bf(tile[tx][ty + i * 8]);
  }
}

// ---------------------------------------------------------------------------
// GEMM core: C = L[128 x N] * R[N x 128] (Rt stored [n][k]).
// R4 structure (best: 128.4 us): 1024 threads = 16 waves = 4 waves/SIMD.
// In-block split-K: half h = w>>3 does K in [h*1024,(h+1)*1024) in its own
// double-buffered pipeline; halves share the block barrier in lockstep.
// Wave sub = w&7 owns a 64x32 subtile -> acc[4][2]. One barrier per step.
//
// NEW vs R4 (single variable): staging via global_load_lds (Common-mistake
// #1; m151: 874 vs 646 TF at 128^2 = +35% over reg-staging). This removes
// 64 ds_write_b128/CU-step and ~32 staging VGPRs. Constraints handled:
//  - LDS must be LINEAR [128][64] (no pad; gload_lds writes base+lane*16).
//  - Unpadded 128B rows => 16-way read conflict, fixed by BOTH-sides XOR
//    swizzle (rule #21): phys chunk c of row r holds logical chunk c^(r&7).
//    Writer: lane's global col = ((lane&7)^(lane>>3))*8 (LDS stays linear).
//    Reader: chunk (kk*4+q) read at ((kk*4+q)^(lr&7))*16 B. Both patterns
//    verified 8-accesses/bank = conflict-minimal.
// RULE #20: all register arrays statically indexed; h selects VALUES only.
// ---------------------------------------------------------------------------
__device__ __forceinline__ void gemm_core(const u16* __restrict__ L,
                                          const u16* __restrict__ Rt,
                                          int row0, int col0,
                                          float res[4][4]) {
  __shared__ __align__(16) u16 As[2][2][TILE * BK];  // [half][buf] 32,768 B
  __shared__ __align__(16) u16 Bs[2][2][TILE * BK];  // [half][buf] 32,768 B

  const int t = threadIdx.x;             // 0..1023
  const int lane = t & 63;
  const int w = t >> 6;                  // 0..15
  const int h = w >> 3;                  // K-half
  const int wv = w & 7;                  // wave within half

  // staging: wave wv covers 8-row groups g0 = wv*2 and g0+1 of both tiles.
  // lane l -> row g*8 + (l>>3), phys chunk l&7; source col chunk (l&7)^(l>>3).
  const int rl = lane >> 3;
  const int cl = ((lane & 7) ^ rl) * 8;  // swizzled source column (u16)
  const int g0 = wv * 2;
  const u16* gA0 = L + (size_t)(row0 + g0 * 8 + rl) * N + h * (KH * BK) + cl;
  const u16* gA1 = gA0 + 8 * N;
  const u16* gB0 = Rt + (size_t)(col0 + g0 * 8 + rl) * N + h * (KH * BK) + cl;
  const u16* gB1 = gB0 + 8 * N;
  const int ld0 = g0 * 512;              // u16 LDS offset of group g0 (1KB/group)

  const int sub = wv;                    // output subtile id (shared by halves)
  const int wr = (sub >> 2) * 64;
  const int wc = (sub & 3) * 32;
  const int lr = lane & 15;
  const int q = lane >> 4;
  const int lx = lr & 7;                 // row&7 for all frag rows (16-aligned)
  const int arow = (wr + lr) * BK;       // u16
  const int brow = (wc + lr) * BK;

  floatx4 acc[4][2];
#pragma unroll
  for (int i = 0; i < 4; i++)
#pragma unroll
    for (int j = 0; j < 2; j++) acc[i][j] = (floatx4){0.f, 0.f, 0.f, 0.f};

  // prologue: tile 0 of this half -> buf 0 (async; barrier drains vmcnt)
  gload16(gA0, &As[h][0][ld0]);
  gload16(gA1, &As[h][0][ld0 + 512]);
  gload16(gB0, &Bs[h][0][ld0]);
  gload16(gB1, &Bs[h][0][ld0 + 512]);
  __syncthreads();

  // step i: issue async loads of tile i+1 into buf[nxt] (its readers drained
  // before the previous barrier); compute on buf[cur]; one barrier (compiler
  // emits vmcnt(0) lgkmcnt(0) drain before s_barrier -> tile i+1 visible).
#define GSTEP(i, cur, nxt)                                                    \
  {                                                                           \
    if ((i) + 1 < KH) {                                                       \
      gload16(gA0 + ((i) + 1) * BK, &As[h][nxt][ld0]);                        \
      gload16(gA1 + ((i) + 1) * BK, &As[h][nxt][ld0 + 512]);                  \
      gload16(gB0 + ((i) + 1) * BK, &Bs[h][nxt][ld0]);                        \
      gload16(gB1 + ((i) + 1) * BK, &Bs[h][nxt][ld0 + 512]);                  \
    }                                                                         \
    _Pragma("unroll") for (int kk = 0; kk < 2; kk++) {                        \
      bf16x8 af[4], bfr[2];                                                   \
      _Pragma("unroll") for (int mt = 0; mt < 4; mt++) af[mt] =               \
          __builtin_bit_cast(                                                 \
              bf16x8, *(const ushortx8*)&As[h][cur][arow + mt * 16 * BK +     \
                                                    ((kk * 4 + q) ^ lx) * 8]); \
      _Pragma("unroll") for (int nt = 0; nt < 2; nt++) bfr[nt] =              \
          __builtin_bit_cast(                                                 \
              bf16x8, *(const ushortx8*)&Bs[h][cur][brow + nt * 16 * BK +     \
                                                    ((kk * 4 + q) ^ lx) * 8]); \
      _Pragma("unroll") for (int mt = 0; mt < 4; mt++)                        \
          _Pragma("unroll") for (int nt = 0; nt < 2; nt++) acc[mt][nt] =      \
              __builtin_amdgcn_mfma_f32_16x16x32_bf16(af[mt], bfr[nt],        \
                                                      acc[mt][nt], 0, 0, 0);  \
    }                                                                         \
    __syncthreads();                                                          \
  }

  for (int io = 0; io < KH; io += 2) {
    GSTEP(io, 0, 1)
    GSTEP(io + 1, 1, 0)
  }
#undef GSTEP

  // K-half pair reduction. Aliases As (dead after the final barrier; all LDS
  // reads and DMA writes drained there). Wave (sub,h) ships its nt=(1-h)
  // column block to slot (sub,1-h); reads partner's from slot (sub,h).
  // 16 slots x 64 x RSTR(16) f32 = 65,536 B == sizeof(As). Static indices;
  // h selects values only (rule #20).
  float* red = (float*)&As[0][0][0];
  const int oh = 1 - h;
  const int rship = (sub * 2 + oh) * (64 * RSTR);
  const int rkeep = (sub * 2 + h) * (64 * RSTR);
#pragma unroll
  for (int mt = 0; mt < 4; mt++)
#pragma unroll
    for (int r = 0; r < 4; r++) {
      const float vship = h ? acc[mt][0][r] : acc[mt][1][r];
      red[rship + (mt * 16 + q * 4 + r) * RSTR + lr] = vship;
    }
  __syncthreads();
#pragma unroll
  for (int mt = 0; mt < 4; mt++)
#pragma unroll
    for (int r = 0; r < 4; r++) {
      const float vkeep = h ? acc[mt][1][r] : acc[mt][0][r];
      res[mt][r] = vkeep + red[rkeep + (mt * 16 + q * 4 + r) * RSTR + lr];
    }
}

// GEMM1: Mb = bf16(A @ A)
__global__ __launch_bounds__(1024, 4) void gemm_aa(const u16* __restrict__ Ab,
                                                   const u16* __restrict__ Abt,
                                                   u16* __restrict__ Mb) {
  const int row0 = blockIdx.y * TILE, col0 = blockIdx.x * TILE;
  float res[4][4];
  gemm_core(Ab, Abt, row0, col0, res);
  const int t = threadIdx.x;
  const int lane = t & 63, w = t >> 6;
  const int sub = w & 7, h = w >> 3;
  const int wr = (sub >> 2) * 64, wc = (sub & 3) * 32;
  const int lr = lane & 15, q = lane >> 4;
  const int cc = col0 + wc + h * 16 + lr;  // kept 16-col block
#pragma unroll
  for (int mt = 0; mt < 4; mt++)
#pragma unroll
    for (int r = 0; r < 4; r++) {
      const int rr = row0 + wr + mt * 16 + q * 4 + r;
      Mb[(size_t)rr * N + cc] = f2bf(res[mt][r]);
    }
}

// rdeg[i] = 1 / (4*rowsum(M)_i + 1)   (with reference's <=1e-10 guard)
__global__ void rowsum_k(const u16* __restrict__ Mb, float* __restrict__ rdeg) {
  const int row = blockIdx.x;
  const int t = threadIdx.x;
  const ushortx8 v = *((const ushortx8*)(Mb + (size_t)row * N) + t);
  float s = 0.f;
#pragma unroll
  for (int j = 0; j < 8; j++) s += bf2f(v[j]);
#pragma unroll
  for (int off = 32; off > 0; off >>= 1) s += __shfl_down(s, off, 64);
  __shared__ float ws[4];
  if ((t & 63) == 0) ws[t >> 6] = s;
  __syncthreads();
  if (t == 0) {
    float d = 4.f * (ws[0] + ws[1] + ws[2] + ws[3]) + 1.f;
    if (d <= 1e-10f) d = 1.f;
    rdeg[row] = 1.f / d;
  }
}

// GEMM2 + fused norm epilogue: out = (8*(M@A) + 2*A) * rdeg[row]
__global__ __launch_bounds__(1024, 4) void gemm_ma(const u16* __restrict__ Mb,
                                                   const u16* __restrict__ Abt,
                                                   const float* __restrict__ A,
                                                   const float* __restrict__ rdeg,
                                                   float* __restrict__ out) {
  const int row0 = blockIdx.y * TILE, col0 = blockIdx.x * TILE;
  float res[4][4];
  gemm_core(Mb, Abt, row0, col0, res);
  const int t = threadIdx.x;
  const int lane = t & 63, w = t >> 6;
  const int sub = w & 7, h = w >> 3;
  const int wr = (sub >> 2) * 64, wc = (sub & 3) * 32;
  const int lr = lane & 15, q = lane >> 4;
  const int cc = col0 + wc + h * 16 + lr;  // kept 16-col block
#pragma unroll
  for (int mt = 0; mt < 4; mt++)
#pragma unroll
    for (int r = 0; r < 4; r++) {
      const int rr = row0 + wr + mt * 16 + q * 4 + r;
      out[(size_t)rr * N + cc] =
          (8.f * res[mt][r] + 2.f * A[(size_t)rr * N + cc]) * rdeg[rr];
    }
}

extern "C" void kernel_launch(void* const* d_in, const int* in_sizes, int n_in,
                              void* d_out, int out_size, void* d_ws, size_t ws_size,
                              hipStream_t stream) {
  const float* A = (const float*)d_in[0];
  // GTConv weights (d_in[1..3]) are irrelevant: softmax over a singleton axis
  // is identically 1, so each conv output is exactly 2*A.
  float* out = (float*)d_out;
  char* ws = (char*)d_ws;
  u16* Ab = (u16*)ws;                          // 8 MB bf16 A row-major
  u16* Abt = (u16*)(ws + NN * 2);              // 8 MB bf16 A transposed
  u16* Mb = (u16*)(ws + NN * 4);               // 8 MB bf16 M = A@A
  float* rdeg = (float*)(ws + NN * 6);         // 8 KB reciprocal degrees

  cast_tr<<<dim3(N / 32, N / 32), dim3(32, 8), 0, stream>>>(A, Ab, Abt);
  gemm_aa<<<dim3(N / TILE, N / TILE), 1024, 0, stream>>>(Ab, Abt, Mb);
  rowsum_k<<<N, 256, 0, stream>>>(Mb, rdeg);
  gemm_ma<<<dim3(N / TILE, N / TILE), 1024, 0, stream>>>(Mb, Abt, A, rdeg, out);
}